// Round 10
// baseline (347.936 us; speedup 1.0000x reference)
//
#include <hip/hip_runtime.h>

// ---------------------------------------------------------------------------
// bf16-MFMA pipeline, round 10: attention K/V double-buffer (1 barrier/tile,
// loads in flight across compute) + s_setprio around MFMA clusters.
// Kr per (var,b,h): 16 tiles x [d8(8)][row(64)][8]; Vt per (b,h): same shape.
// ws layout (MiB):
//   [0,16)   hb  -> reused as Vt after QKV GEMM
//   [16,22)  wqkvb   [22,24) wob
//   [24,40)  qb
//   [40,56)  kb \ -> reused as attn0 (f32 32MiB) after rope
//   [56,72)  vb /
//   [72,104) Kr
//   [104,120) attnavg bf16
// d_out = f32 scratch for attn var1, then final GEMM output.
// ---------------------------------------------------------------------------

typedef __attribute__((ext_vector_type(8))) short s16x8;
typedef __attribute__((ext_vector_type(4))) float f32x4;
typedef __attribute__((ext_vector_type(16))) float f32x16;
typedef unsigned short ushort_t;

__device__ __forceinline__ float bf2f(unsigned short u) {
    unsigned x = ((unsigned)u) << 16;
    return __builtin_bit_cast(float, x);
}
__device__ __forceinline__ unsigned short f2bf(float f) {
    unsigned u = __builtin_bit_cast(unsigned, f);
    unsigned r = (u + 0x7fffu + ((u >> 16) & 1u)) >> 16;
    return (unsigned short)r;
}
__device__ __forceinline__ f32x4 mfma16(s16x8 a, s16x8 b, f32x4 c) {
    return __builtin_amdgcn_mfma_f32_16x16x32_bf16(a, b, c, 0, 0, 0);
}
__device__ __forceinline__ f32x16 mfma32(s16x8 a, s16x8 b, f32x16 c) {
    return __builtin_amdgcn_mfma_f32_32x32x16_bf16(a, b, c, 0, 0, 0);
}
__device__ __forceinline__ void gload16(const ushort_t* g, ushort_t* lds) {
    __builtin_amdgcn_global_load_lds(
        (const __attribute__((address_space(1))) unsigned int*)g,
        (__attribute__((address_space(3))) unsigned int*)lds, 16, 0, 0);
}
__device__ __forceinline__ float4 ld4f(const float* p) { return *reinterpret_cast<const float4*>(p); }
__device__ __forceinline__ s16x8 ldg8(const ushort_t* p) { return *reinterpret_cast<const s16x8*>(p); }

__device__ __forceinline__ unsigned cvtpk(float lo, float hi) {
    unsigned r;
    asm("v_cvt_pk_bf16_f32 %0, %1, %2" : "=v"(r) : "v"(lo), "v"(hi));
    return r;
}
__device__ __forceinline__ void pl32swap(unsigned& a, unsigned& b, int hi) {
#if __has_builtin(__builtin_amdgcn_permlane32_swap)
    auto r = __builtin_amdgcn_permlane32_swap((int)a, (int)b, false, false);
    a = (unsigned)r[0]; b = (unsigned)r[1];
#else
    unsigned sa = (unsigned)__shfl_xor((int)a, 32);
    unsigned sb = (unsigned)__shfl_xor((int)b, 32);
    unsigned na = hi ? sb : a;
    unsigned nb = hi ? b : sa;
    a = na; b = nb;
#endif
}
__device__ __forceinline__ s16x8 frag4(unsigned w0, unsigned w1, unsigned w2, unsigned w3) {
    union { unsigned u[4]; s16x8 v; } t;
    t.u[0] = w0; t.u[1] = w1; t.u[2] = w2; t.u[3] = w3;
    return t.v;
}

// ---------------- merged f32 -> bf16 convert (3 segments, 1 launch) ---------
__global__ __launch_bounds__(256) void conv3(
    const float* __restrict__ sA, ushort_t* __restrict__ dA, int nA,
    const float* __restrict__ sB, ushort_t* __restrict__ dB, int nB,
    const float* __restrict__ sC, ushort_t* __restrict__ dC, int nC)
{
    const int total = nA + nB + nC;
    int i = blockIdx.x * blockDim.x + threadIdx.x;
    const int str = gridDim.x * blockDim.x;
    for (; i < total; i += str) {
        const float* s; ushort_t* d; int off;
        if (i < nA)           { s = sA; d = dA; off = i; }
        else if (i < nA + nB) { s = sB; d = dB; off = i - nA; }
        else                  { s = sC; d = dC; off = i - nA - nB; }
        float4 a = ld4f(s + (size_t)off * 8);
        float4 b = ld4f(s + (size_t)off * 8 + 4);
        s16x8 o;
        o[0] = (short)f2bf(a.x); o[1] = (short)f2bf(a.y); o[2] = (short)f2bf(a.z); o[3] = (short)f2bf(a.w);
        o[4] = (short)f2bf(b.x); o[5] = (short)f2bf(b.y); o[6] = (short)f2bf(b.z); o[7] = (short)f2bf(b.w);
        *reinterpret_cast<s16x8*>(d + (size_t)off * 8) = o;
    }
}

// ---------------- o = bf16(0.5*(a+b)) ----------------
__global__ __launch_bounds__(256) void avg_to_bf16(const float* __restrict__ a,
                                                   const float* __restrict__ b,
                                                   ushort_t* __restrict__ o, int n8)
{
    int i = blockIdx.x * blockDim.x + threadIdx.x;
    const int str = gridDim.x * blockDim.x;
    for (; i < n8; i += str) {
        float4 x0 = ld4f(a + (size_t)i * 8), x1 = ld4f(a + (size_t)i * 8 + 4);
        float4 y0 = ld4f(b + (size_t)i * 8), y1 = ld4f(b + (size_t)i * 8 + 4);
        s16x8 v;
        v[0] = (short)f2bf(0.5f * (x0.x + y0.x)); v[1] = (short)f2bf(0.5f * (x0.y + y0.y));
        v[2] = (short)f2bf(0.5f * (x0.z + y0.z)); v[3] = (short)f2bf(0.5f * (x0.w + y0.w));
        v[4] = (short)f2bf(0.5f * (x1.x + y1.x)); v[5] = (short)f2bf(0.5f * (x1.y + y1.y));
        v[6] = (short)f2bf(0.5f * (x1.z + y1.z)); v[7] = (short)f2bf(0.5f * (x1.w + y1.w));
        *reinterpret_cast<s16x8*>(o + (size_t)i * 8) = v;
    }
}

// ---------------- MFMA GEMM (unchanged, validated) ----------------
template<bool SPLIT_QKV>
__global__ __launch_bounds__(256) void gemm_mfma(const ushort_t* __restrict__ A,
                                                 const ushort_t* __restrict__ B,
                                                 void* __restrict__ C0, void* __restrict__ C1,
                                                 void* __restrict__ C2,
                                                 int M, int N, int K)
{
    __shared__ ushort_t As[128 * 64];
    __shared__ ushort_t Bs[128 * 64];
    const int tid = threadIdx.x, l = tid & 63, w = tid >> 6;
    const int lr = l & 15, lg = l >> 4;
    const int m0 = blockIdx.y * 128, n0 = blockIdx.x * 128;
    const int wr = w >> 1, wc = w & 1;

    int srow[4], scol[4];
#pragma unroll
    for (int i = 0; i < 4; ++i) {
        const int chunk = i * 4 + w;
        const int row = chunk * 8 + (l >> 3);
        srow[i] = row;
        scol[i] = ((l & 7) ^ (row & 7)) * 8;
    }

    f32x4 acc[4][4];
#pragma unroll
    for (int mi = 0; mi < 4; ++mi)
#pragma unroll
        for (int ni = 0; ni < 4; ++ni) acc[mi][ni] = (f32x4){0.f, 0.f, 0.f, 0.f};

    for (int k0 = 0; k0 < K; k0 += 64) {
        __syncthreads();
#pragma unroll
        for (int i = 0; i < 4; ++i) {
            gload16(A + (size_t)(m0 + srow[i]) * K + k0 + scol[i], &As[(i * 4 + w) * 512]);
            gload16(B + (size_t)(n0 + srow[i]) * K + k0 + scol[i], &Bs[(i * 4 + w) * 512]);
        }
        __syncthreads();
#pragma unroll
        for (int kf = 0; kf < 2; ++kf) {
            s16x8 af[4], bf[4];
#pragma unroll
            for (int mi = 0; mi < 4; ++mi) {
                const int row = wr * 64 + mi * 16 + lr;
                af[mi] = *reinterpret_cast<const s16x8*>(&As[row * 64 + (((kf * 4 + lg) ^ (row & 7)) << 3)]);
            }
#pragma unroll
            for (int ni = 0; ni < 4; ++ni) {
                const int row = wc * 64 + ni * 16 + lr;
                bf[ni] = *reinterpret_cast<const s16x8*>(&Bs[row * 64 + (((kf * 4 + lg) ^ (row & 7)) << 3)]);
            }
#pragma unroll
            for (int mi = 0; mi < 4; ++mi)
#pragma unroll
                for (int ni = 0; ni < 4; ++ni)
                    acc[mi][ni] = mfma16(af[mi], bf[ni], acc[mi][ni]);
        }
    }

    if (SPLIT_QKV) {
        ushort_t* Cb = (ushort_t*)(n0 < 1024 ? C0 : (n0 < 2048 ? C1 : C2));
        const int nbase = n0 & 1023;
#pragma unroll
        for (int mi = 0; mi < 4; ++mi)
#pragma unroll
            for (int q = 0; q < 4; ++q) {
                const int row = m0 + wr * 64 + mi * 16 + lg * 4 + q;
#pragma unroll
                for (int ni = 0; ni < 4; ++ni)
                    Cb[(size_t)row * 1024 + nbase + wc * 64 + ni * 16 + lr] = f2bf(acc[mi][ni][q]);
            }
    } else {
#pragma unroll
        for (int mi = 0; mi < 4; ++mi)
#pragma unroll
            for (int q = 0; q < 4; ++q) {
                const int row = m0 + wr * 64 + mi * 16 + lg * 4 + q;
#pragma unroll
                for (int ni = 0; ni < 4; ++ni)
                    ((float*)C0)[(size_t)row * N + n0 + wc * 64 + ni * 16 + lr] = acc[mi][ni][q];
            }
    }
}

// ---------------- RoPE(K) both variants + V^T, frag-linear tile layouts -----
__global__ __launch_bounds__(256) void rope_rearrange(
    const ushort_t* __restrict__ kb, const ushort_t* __restrict__ vb,
    const float* __restrict__ cosp, const float* __restrict__ sinp,
    ushort_t* __restrict__ Kr, ushort_t* __restrict__ Vt)
{
    __shared__ ushort_t Vs[64 * 65];
    const int tid = threadIdx.x;
    const int sblk = blockIdx.x, h = blockIdx.y, b = blockIdx.z;
    const int r = tid >> 2, c16 = (tid & 3) * 16;
    const int cc = c16 ^ 32;
    const float sg = (c16 < 32) ? -1.f : 1.f;
    const int s = sblk * 64 + r;

    const ushort_t* krow = kb + (size_t)(b * 1024 + s) * 1024 + h * 64;
    const ushort_t* vrow = vb + (size_t)(b * 1024 + s) * 1024 + h * 64;

    s16x8 kx0 = ldg8(krow + c16), kx1 = ldg8(krow + c16 + 8);
    s16x8 ky0 = ldg8(krow + cc),  ky1 = ldg8(krow + cc + 8);

#pragma unroll
    for (int var = 0; var < 2; ++var) {
        const int pos = var ? ((s & 31) * 32 + (s >> 5)) : s;
        const float* crow = cosp + (size_t)pos * 64 + c16;
        const float* srow = sinp + (size_t)pos * 64 + c16;
        ushort_t* kout = Kr + (((size_t)(var * 8 + b) * 16 + h) * 65536)
                            + (size_t)sblk * 4096 + (c16 >> 3) * 512 + r * 8;
        s16x8 o0, o1;
#pragma unroll
        for (int j = 0; j < 8; ++j) {
            o0[j] = (short)f2bf(bf2f((unsigned short)kx0[j]) * crow[j]
                     + sg * bf2f((unsigned short)ky0[j]) * srow[j]);
            o1[j] = (short)f2bf(bf2f((unsigned short)kx1[j]) * crow[j + 8]
                     + sg * bf2f((unsigned short)ky1[j]) * srow[j + 8]);
        }
        *reinterpret_cast<s16x8*>(kout) = o0;
        *reinterpret_cast<s16x8*>(kout + 512) = o1;
    }

    s16x8 v0 = ldg8(vrow + c16), v1 = ldg8(vrow + c16 + 8);
#pragma unroll
    for (int j = 0; j < 8; ++j) {
        Vs[r * 65 + c16 + j] = (ushort_t)v0[j];
        Vs[r * 65 + c16 + 8 + j] = (ushort_t)v1[j];
    }
    __syncthreads();
    {
        const int dd = tid >> 2, cs = (tid & 3) * 16;
        s16x8 t0, t1;
#pragma unroll
        for (int j = 0; j < 8; ++j) {
            t0[j] = (short)Vs[(cs + j) * 65 + dd];
            t1[j] = (short)Vs[(cs + 8 + j) * 65 + dd];
        }
        ushort_t* vout = Vt + ((size_t)(b * 16 + h) * 65536)
                            + (size_t)sblk * 4096 + (cs >> 3) * 512 + dd * 8;
        *reinterpret_cast<s16x8*>(vout) = t0;
        *reinterpret_cast<s16x8*>(vout + 512) = t1;
    }
}

// ---------------- attention v7: K/V double-buffer + setprio ----------------
// One barrier per kt tile: stage(next -> buf^1) issued BEFORE compute(buf);
// the barrier's implicit vmcnt(0) lands AFTER compute, so loads fly under
// MFMA+softmax. Race-safe: buf^1 was fully read before prior barrier.
__global__ __launch_bounds__(256) void attn_mfma7(
    const ushort_t* __restrict__ qb,
    const ushort_t* __restrict__ Kr,
    const ushort_t* __restrict__ Vt,
    const float* __restrict__ cosp, const float* __restrict__ sinp,
    float* __restrict__ out0, float* __restrict__ out1)
{
    __shared__ ushort_t Qs[128 * 64];
    __shared__ ushort_t Ks[2][64 * 64];
    __shared__ ushort_t Vs[2][64 * 64];

    const int bi = blockIdx.x;
    const int qt = (bi >> 3) & 7;
    const int g = ((bi >> 6) << 3) | (bi & 7);
    const int h = g & 15, bz = g >> 4;
    const int b = bz >> 1, var = bz & 1;

    const int tid = threadIdx.x;
    const int l = tid & 63, wq = tid >> 6;
    const int l31 = l & 31, hi = l >> 5;
    const int s0 = qt * 128;

    const ushort_t* kr_base = Kr + ((size_t)(var * 8 + b) * 16 + h) * 65536;
    const ushort_t* vt_base = Vt + ((size_t)(b * 16 + h)) * 65536;
    const int chunk0 = wq * 2, chunk1 = wq * 2 + 1;
    const int loff0 = chunk0 * 512 + l * 8, loff1 = chunk1 * 512 + l * 8;

    // ---- prologue: issue tile-0 loads, then stage Q while they fly ----
    gload16(kr_base + loff0, &Ks[0][chunk0 * 512]);
    gload16(kr_base + loff1, &Ks[0][chunk1 * 512]);
    gload16(vt_base + loff0, &Vs[0][chunk0 * 512]);
    gload16(vt_base + loff1, &Vs[0][chunk1 * 512]);

    {
        const int r = tid >> 1;
        const int half = tid & 1;
        const int c32 = half * 32, cco = 32 - c32;
        const float sg = half ? 1.f : -1.f;
        const int p = s0 + r;
        const int pos = var ? ((p & 31) * 32 + (p >> 5)) : p;
        const ushort_t* qrow = qb + (size_t)(b * 1024 + p) * 1024 + h * 64;
        const float* crow = cosp + (size_t)pos * 64 + c32;
        const float* srow = sinp + (size_t)pos * 64 + c32;
        constexpr float SCALE = 0.125f * 1.44269504f;
#pragma unroll
        for (int u = 0; u < 4; ++u) {
            s16x8 xv = ldg8(qrow + c32 + u * 8);
            s16x8 yv = ldg8(qrow + cco + u * 8);
            s16x8 ov;
#pragma unroll
            for (int j = 0; j < 8; ++j) {
                const int e = u * 8 + j;
                ov[j] = (short)f2bf((bf2f((unsigned short)xv[j]) * crow[e]
                         + sg * bf2f((unsigned short)yv[j]) * srow[e]) * SCALE);
            }
            *reinterpret_cast<s16x8*>(&Qs[((half * 4 + u) * 128 + r) * 8]) = ov;
        }
    }
    __syncthreads();   // Q visible + tile-0 K/V loaded (implicit vmcnt/lgkm drain)

    s16x8 qf[4];
    {
        const int qrow = wq * 32 + l31;
#pragma unroll
        for (int kc = 0; kc < 4; ++kc)
            qf[kc] = *reinterpret_cast<const s16x8*>(&Qs[((2 * kc + hi) * 128 + qrow) * 8]);
    }

    float l_i = 0.f;
    f32x16 O0, O1;
#pragma unroll
    for (int r = 0; r < 16; ++r) { O0[r] = 0.f; O1[r] = 0.f; }

    int cur = 0;
    for (int kt = 0; kt < 16; ++kt) {
        // ---- issue next tile's loads into the other buffer ----
        if (kt < 15) {
            const size_t nb = (size_t)(kt + 1) * 4096;
            gload16(kr_base + nb + loff0, &Ks[cur ^ 1][chunk0 * 512]);
            gload16(kr_base + nb + loff1, &Ks[cur ^ 1][chunk1 * 512]);
            gload16(vt_base + nb + loff0, &Vs[cur ^ 1][chunk0 * 512]);
            gload16(vt_base + nb + loff1, &Vs[cur ^ 1][chunk1 * 512]);
        }

        // ---- S^T = mfma32(K, Q) ----
        f32x16 St0, St1;
#pragma unroll
        for (int r = 0; r < 16; ++r) { St0[r] = 0.f; St1[r] = 0.f; }
        __builtin_amdgcn_s_setprio(1);
#pragma unroll
        for (int kc = 0; kc < 4; ++kc) {
            const int d8 = 2 * kc + hi;
            s16x8 kf0 = *reinterpret_cast<const s16x8*>(&Ks[cur][d8 * 512 + l31 * 8]);
            s16x8 kf1 = *reinterpret_cast<const s16x8*>(&Ks[cur][d8 * 512 + (32 + l31) * 8]);
            St0 = mfma32(kf0, qf[kc], St0);
            St1 = mfma32(kf1, qf[kc], St1);
        }
        __builtin_amdgcn_s_setprio(0);

        // ---- fixed-max softmax: P = exp2(S) ----
        float rs0 = 0.f, rs1 = 0.f;
#pragma unroll
        for (int r = 0; r < 16; ++r) { St0[r] = __builtin_amdgcn_exp2f(St0[r]); rs0 += St0[r]; }
#pragma unroll
        for (int r = 0; r < 16; ++r) { St1[r] = __builtin_amdgcn_exp2f(St1[r]); rs1 += St1[r]; }
        l_i += rs0 + rs1;

        // ---- P^T frags; O^T += V^T P^T ----
        __builtin_amdgcn_s_setprio(1);
#pragma unroll
        for (int t = 0; t < 2; ++t) {
            unsigned w0, w1, w2, w3, w4, w5, w6, w7;
            if (t == 0) {
                w0 = cvtpk(St0[0], St0[1]);   w1 = cvtpk(St0[2], St0[3]);
                w2 = cvtpk(St0[4], St0[5]);   w3 = cvtpk(St0[6], St0[7]);
                w4 = cvtpk(St0[8], St0[9]);   w5 = cvtpk(St0[10], St0[11]);
                w6 = cvtpk(St0[12], St0[13]); w7 = cvtpk(St0[14], St0[15]);
            } else {
                w0 = cvtpk(St1[0], St1[1]);   w1 = cvtpk(St1[2], St1[3]);
                w2 = cvtpk(St1[4], St1[5]);   w3 = cvtpk(St1[6], St1[7]);
                w4 = cvtpk(St1[8], St1[9]);   w5 = cvtpk(St1[10], St1[11]);
                w6 = cvtpk(St1[12], St1[13]); w7 = cvtpk(St1[14], St1[15]);
            }
            pl32swap(w0, w2, hi);
            pl32swap(w1, w3, hi);
            pl32swap(w4, w6, hi);
            pl32swap(w5, w7, hi);
            const s16x8 pf0 = frag4(w0, w1, w2, w3);
            const s16x8 pf1 = frag4(w4, w5, w6, w7);
#pragma unroll
            for (int cc = 0; cc < 2; ++cc) {
                const int sg8 = 2 * (2 * t + cc) + hi;
                const s16x8 pf = cc ? pf1 : pf0;
                s16x8 vf0 = *reinterpret_cast<const s16x8*>(&Vs[cur][sg8 * 512 + l31 * 8]);
                s16x8 vf1 = *reinterpret_cast<const s16x8*>(&Vs[cur][sg8 * 512 + (32 + l31) * 8]);
                O0 = mfma32(vf0, pf, O0);
                O1 = mfma32(vf1, pf, O1);
            }
        }
        __builtin_amdgcn_s_setprio(0);

        __syncthreads();   // drains vmcnt -> next tile staged; all reads of cur done
        cur ^= 1;
    }

    // ---- epilogue ----
    float* outp = var ? out1 : out0;
    const float inv = 1.f / (l_i + __shfl_xor(l_i, 32));
    const int qrow = s0 + wq * 32 + l31;
    float* orow = outp + (size_t)(b * 1024 + qrow) * 1024 + h * 64;
#pragma unroll
    for (int gq = 0; gq < 4; ++gq) {
        const int d0 = 8 * gq + 4 * hi;
        *reinterpret_cast<float4*>(orow + d0) =
            make_float4(O0[4 * gq] * inv, O0[4 * gq + 1] * inv, O0[4 * gq + 2] * inv, O0[4 * gq + 3] * inv);
        *reinterpret_cast<float4*>(orow + 32 + d0) =
            make_float4(O1[4 * gq] * inv, O1[4 * gq + 1] * inv, O1[4 * gq + 2] * inv, O1[4 * gq + 3] * inv);
    }
}

extern "C" void kernel_launch(void* const* d_in, const int* in_sizes, int n_in,
                              void* d_out, int out_size, void* d_ws, size_t ws_size,
                              hipStream_t stream) {
    const float* hidden = (const float*)d_in[0];
    const float* cosp   = (const float*)d_in[1];
    const float* sinp   = (const float*)d_in[2];
    const float* wqkv   = (const float*)d_in[3];
    const float* wo     = (const float*)d_in[4];
    float* out = (float*)d_out;

    char* wsb = (char*)d_ws;
    ushort_t* hb      = (ushort_t*)(wsb);                   // [0,16M)
    ushort_t* wqkvb   = (ushort_t*)(wsb + (16ull << 20));   // [16,22M)
    ushort_t* wob     = (ushort_t*)(wsb + (22ull << 20));   // [22,24M)
    ushort_t* qb      = (ushort_t*)(wsb + (24ull << 20));   // [24,40M)
    ushort_t* kb      = (ushort_t*)(wsb + (40ull << 20));   // [40,56M)
    ushort_t* vb      = (ushort_t*)(wsb + (56ull << 20));   // [56,72M)
    float*    attn0   = (float*)   (wsb + (40ull << 20));   // [40,72M) overlays kb,vb
    ushort_t* Kr      = (ushort_t*)(wsb + (72ull << 20));   // [72,104M)
    ushort_t* Vt      = hb;                                 // overlays hb (dead after QKV GEMM)
    ushort_t* attnavg = (ushort_t*)(wsb + (104ull << 20));  // [104,120M)

    conv3<<<1536, 256, 0, stream>>>(hidden, hb, 8192 * 1024 / 8,
                                    wqkv, wqkvb, 3072 * 1024 / 8,
                                    wo, wob, 1024 * 1024 / 8);

    gemm_mfma<true><<<dim3(24, 64), 256, 0, stream>>>(hb, wqkvb, qb, kb, vb, 8192, 3072, 1024);

    rope_rearrange<<<dim3(16, 16, 8), 256, 0, stream>>>(kb, vb, cosp, sinp, Kr, Vt);

    attn_mfma7<<<2048, 256, 0, stream>>>(qb, Kr, Vt, cosp, sinp, attn0, out);

    avg_to_bf16<<<2048, 256, 0, stream>>>(attn0, out, attnavg, 8192 * 1024 / 8);

    gemm_mfma<false><<<dim3(8, 64), 256, 0, stream>>>(attnavg, wob, out, nullptr, nullptr, 8192, 1024, 1024);
}

// Round 11
// 302.782 us; speedup vs baseline: 1.1491x; 1.1491x over previous
//
#include <hip/hip_runtime.h>

// ---------------------------------------------------------------------------
// bf16-MFMA pipeline, round 11: v6 attention structure with QBLK=256 (8 waves,
// K/V staged once per 256 q-rows), XCD-chunked GEMM block mapping.
// Kr per (var,b,h): 16 tiles x [d8(8)][row(64)][8]; Vt per (b,h): same shape.
// ws layout (MiB):
//   [0,16)   hb  -> reused as Vt after QKV GEMM
//   [16,22)  wqkvb   [22,24) wob
//   [24,40)  qb
//   [40,56)  kb \ -> reused as attn0 (f32 32MiB) after rope
//   [56,72)  vb /
//   [72,104) Kr
//   [104,120) attnavg bf16
// d_out = f32 scratch for attn var1, then final GEMM output.
// ---------------------------------------------------------------------------

typedef __attribute__((ext_vector_type(8))) short s16x8;
typedef __attribute__((ext_vector_type(4))) float f32x4;
typedef __attribute__((ext_vector_type(16))) float f32x16;
typedef unsigned short ushort_t;

__device__ __forceinline__ float bf2f(unsigned short u) {
    unsigned x = ((unsigned)u) << 16;
    return __builtin_bit_cast(float, x);
}
__device__ __forceinline__ unsigned short f2bf(float f) {
    unsigned u = __builtin_bit_cast(unsigned, f);
    unsigned r = (u + 0x7fffu + ((u >> 16) & 1u)) >> 16;
    return (unsigned short)r;
}
__device__ __forceinline__ f32x4 mfma16(s16x8 a, s16x8 b, f32x4 c) {
    return __builtin_amdgcn_mfma_f32_16x16x32_bf16(a, b, c, 0, 0, 0);
}
__device__ __forceinline__ f32x16 mfma32(s16x8 a, s16x8 b, f32x16 c) {
    return __builtin_amdgcn_mfma_f32_32x32x16_bf16(a, b, c, 0, 0, 0);
}
__device__ __forceinline__ void gload16(const ushort_t* g, ushort_t* lds) {
    __builtin_amdgcn_global_load_lds(
        (const __attribute__((address_space(1))) unsigned int*)g,
        (__attribute__((address_space(3))) unsigned int*)lds, 16, 0, 0);
}
__device__ __forceinline__ float4 ld4f(const float* p) { return *reinterpret_cast<const float4*>(p); }
__device__ __forceinline__ s16x8 ldg8(const ushort_t* p) { return *reinterpret_cast<const s16x8*>(p); }

__device__ __forceinline__ unsigned cvtpk(float lo, float hi) {
    unsigned r;
    asm("v_cvt_pk_bf16_f32 %0, %1, %2" : "=v"(r) : "v"(lo), "v"(hi));
    return r;
}
__device__ __forceinline__ void pl32swap(unsigned& a, unsigned& b, int hi) {
#if __has_builtin(__builtin_amdgcn_permlane32_swap)
    auto r = __builtin_amdgcn_permlane32_swap((int)a, (int)b, false, false);
    a = (unsigned)r[0]; b = (unsigned)r[1];
#else
    unsigned sa = (unsigned)__shfl_xor((int)a, 32);
    unsigned sb = (unsigned)__shfl_xor((int)b, 32);
    unsigned na = hi ? sb : a;
    unsigned nb = hi ? b : sa;
    a = na; b = nb;
#endif
}
__device__ __forceinline__ s16x8 frag4(unsigned w0, unsigned w1, unsigned w2, unsigned w3) {
    union { unsigned u[4]; s16x8 v; } t;
    t.u[0] = w0; t.u[1] = w1; t.u[2] = w2; t.u[3] = w3;
    return t.v;
}

// ---------------- merged f32 -> bf16 convert (3 segments, 1 launch) ---------
__global__ __launch_bounds__(256) void conv3(
    const float* __restrict__ sA, ushort_t* __restrict__ dA, int nA,
    const float* __restrict__ sB, ushort_t* __restrict__ dB, int nB,
    const float* __restrict__ sC, ushort_t* __restrict__ dC, int nC)
{
    const int total = nA + nB + nC;
    int i = blockIdx.x * blockDim.x + threadIdx.x;
    const int str = gridDim.x * blockDim.x;
    for (; i < total; i += str) {
        const float* s; ushort_t* d; int off;
        if (i < nA)           { s = sA; d = dA; off = i; }
        else if (i < nA + nB) { s = sB; d = dB; off = i - nA; }
        else                  { s = sC; d = dC; off = i - nA - nB; }
        float4 a = ld4f(s + (size_t)off * 8);
        float4 b = ld4f(s + (size_t)off * 8 + 4);
        s16x8 o;
        o[0] = (short)f2bf(a.x); o[1] = (short)f2bf(a.y); o[2] = (short)f2bf(a.z); o[3] = (short)f2bf(a.w);
        o[4] = (short)f2bf(b.x); o[5] = (short)f2bf(b.y); o[6] = (short)f2bf(b.z); o[7] = (short)f2bf(b.w);
        *reinterpret_cast<s16x8*>(d + (size_t)off * 8) = o;
    }
}

// ---------------- o = bf16(0.5*(a+b)) ----------------
__global__ __launch_bounds__(256) void avg_to_bf16(const float* __restrict__ a,
                                                   const float* __restrict__ b,
                                                   ushort_t* __restrict__ o, int n8)
{
    int i = blockIdx.x * blockDim.x + threadIdx.x;
    const int str = gridDim.x * blockDim.x;
    for (; i < n8; i += str) {
        float4 x0 = ld4f(a + (size_t)i * 8), x1 = ld4f(a + (size_t)i * 8 + 4);
        float4 y0 = ld4f(b + (size_t)i * 8), y1 = ld4f(b + (size_t)i * 8 + 4);
        s16x8 v;
        v[0] = (short)f2bf(0.5f * (x0.x + y0.x)); v[1] = (short)f2bf(0.5f * (x0.y + y0.y));
        v[2] = (short)f2bf(0.5f * (x0.z + y0.z)); v[3] = (short)f2bf(0.5f * (x0.w + y0.w));
        v[4] = (short)f2bf(0.5f * (x1.x + y1.x)); v[5] = (short)f2bf(0.5f * (x1.y + y1.y));
        v[6] = (short)f2bf(0.5f * (x1.z + y1.z)); v[7] = (short)f2bf(0.5f * (x1.w + y1.w));
        *reinterpret_cast<s16x8*>(o + (size_t)i * 8) = v;
    }
}

// ---------------- MFMA GEMM: 1-D grid, XCD-chunked block mapping -----------
// wgid = (bid&7)*(nwg/8) + (bid>>3): each XCD gets a contiguous chunk of
// n-fastest tile ids -> same-m A-panels L2-resident per XCD. nwg % 8 == 0.
template<bool SPLIT_QKV>
__global__ __launch_bounds__(256) void gemm_mfma(const ushort_t* __restrict__ A,
                                                 const ushort_t* __restrict__ B,
                                                 void* __restrict__ C0, void* __restrict__ C1,
                                                 void* __restrict__ C2,
                                                 int M, int N, int K, int nX)
{
    __shared__ ushort_t As[128 * 64];
    __shared__ ushort_t Bs[128 * 64];
    const int tid = threadIdx.x, l = tid & 63, w = tid >> 6;
    const int lr = l & 15, lg = l >> 4;
    const int nwg8 = (gridDim.x >> 3);
    const int wgid = (blockIdx.x & 7) * nwg8 + (blockIdx.x >> 3);
    const int m0 = (wgid / nX) * 128, n0 = (wgid % nX) * 128;
    const int wr = w >> 1, wc = w & 1;

    int srow[4], scol[4];
#pragma unroll
    for (int i = 0; i < 4; ++i) {
        const int chunk = i * 4 + w;
        const int row = chunk * 8 + (l >> 3);
        srow[i] = row;
        scol[i] = ((l & 7) ^ (row & 7)) * 8;
    }

    f32x4 acc[4][4];
#pragma unroll
    for (int mi = 0; mi < 4; ++mi)
#pragma unroll
        for (int ni = 0; ni < 4; ++ni) acc[mi][ni] = (f32x4){0.f, 0.f, 0.f, 0.f};

    for (int k0 = 0; k0 < K; k0 += 64) {
        __syncthreads();
#pragma unroll
        for (int i = 0; i < 4; ++i) {
            gload16(A + (size_t)(m0 + srow[i]) * K + k0 + scol[i], &As[(i * 4 + w) * 512]);
            gload16(B + (size_t)(n0 + srow[i]) * K + k0 + scol[i], &Bs[(i * 4 + w) * 512]);
        }
        __syncthreads();
#pragma unroll
        for (int kf = 0; kf < 2; ++kf) {
            s16x8 af[4], bf[4];
#pragma unroll
            for (int mi = 0; mi < 4; ++mi) {
                const int row = wr * 64 + mi * 16 + lr;
                af[mi] = *reinterpret_cast<const s16x8*>(&As[row * 64 + (((kf * 4 + lg) ^ (row & 7)) << 3)]);
            }
#pragma unroll
            for (int ni = 0; ni < 4; ++ni) {
                const int row = wc * 64 + ni * 16 + lr;
                bf[ni] = *reinterpret_cast<const s16x8*>(&Bs[row * 64 + (((kf * 4 + lg) ^ (row & 7)) << 3)]);
            }
#pragma unroll
            for (int mi = 0; mi < 4; ++mi)
#pragma unroll
                for (int ni = 0; ni < 4; ++ni)
                    acc[mi][ni] = mfma16(af[mi], bf[ni], acc[mi][ni]);
        }
    }

    if (SPLIT_QKV) {
        ushort_t* Cb = (ushort_t*)(n0 < 1024 ? C0 : (n0 < 2048 ? C1 : C2));
        const int nbase = n0 & 1023;
#pragma unroll
        for (int mi = 0; mi < 4; ++mi)
#pragma unroll
            for (int q = 0; q < 4; ++q) {
                const int row = m0 + wr * 64 + mi * 16 + lg * 4 + q;
#pragma unroll
                for (int ni = 0; ni < 4; ++ni)
                    Cb[(size_t)row * 1024 + nbase + wc * 64 + ni * 16 + lr] = f2bf(acc[mi][ni][q]);
            }
    } else {
#pragma unroll
        for (int mi = 0; mi < 4; ++mi)
#pragma unroll
            for (int q = 0; q < 4; ++q) {
                const int row = m0 + wr * 64 + mi * 16 + lg * 4 + q;
#pragma unroll
                for (int ni = 0; ni < 4; ++ni)
                    ((float*)C0)[(size_t)row * N + n0 + wc * 64 + ni * 16 + lr] = acc[mi][ni][q];
            }
    }
}

// ---------------- RoPE(K) both variants + V^T, frag-linear tile layouts -----
__global__ __launch_bounds__(256) void rope_rearrange(
    const ushort_t* __restrict__ kb, const ushort_t* __restrict__ vb,
    const float* __restrict__ cosp, const float* __restrict__ sinp,
    ushort_t* __restrict__ Kr, ushort_t* __restrict__ Vt)
{
    __shared__ ushort_t Vs[64 * 65];
    const int tid = threadIdx.x;
    const int sblk = blockIdx.x, h = blockIdx.y, b = blockIdx.z;
    const int r = tid >> 2, c16 = (tid & 3) * 16;
    const int cc = c16 ^ 32;
    const float sg = (c16 < 32) ? -1.f : 1.f;
    const int s = sblk * 64 + r;

    const ushort_t* krow = kb + (size_t)(b * 1024 + s) * 1024 + h * 64;
    const ushort_t* vrow = vb + (size_t)(b * 1024 + s) * 1024 + h * 64;

    s16x8 kx0 = ldg8(krow + c16), kx1 = ldg8(krow + c16 + 8);
    s16x8 ky0 = ldg8(krow + cc),  ky1 = ldg8(krow + cc + 8);

#pragma unroll
    for (int var = 0; var < 2; ++var) {
        const int pos = var ? ((s & 31) * 32 + (s >> 5)) : s;
        const float* crow = cosp + (size_t)pos * 64 + c16;
        const float* srow = sinp + (size_t)pos * 64 + c16;
        ushort_t* kout = Kr + (((size_t)(var * 8 + b) * 16 + h) * 65536)
                            + (size_t)sblk * 4096 + (c16 >> 3) * 512 + r * 8;
        s16x8 o0, o1;
#pragma unroll
        for (int j = 0; j < 8; ++j) {
            o0[j] = (short)f2bf(bf2f((unsigned short)kx0[j]) * crow[j]
                     + sg * bf2f((unsigned short)ky0[j]) * srow[j]);
            o1[j] = (short)f2bf(bf2f((unsigned short)kx1[j]) * crow[j + 8]
                     + sg * bf2f((unsigned short)ky1[j]) * srow[j + 8]);
        }
        *reinterpret_cast<s16x8*>(kout) = o0;
        *reinterpret_cast<s16x8*>(kout + 512) = o1;
    }

    s16x8 v0 = ldg8(vrow + c16), v1 = ldg8(vrow + c16 + 8);
#pragma unroll
    for (int j = 0; j < 8; ++j) {
        Vs[r * 65 + c16 + j] = (ushort_t)v0[j];
        Vs[r * 65 + c16 + 8 + j] = (ushort_t)v1[j];
    }
    __syncthreads();
    {
        const int dd = tid >> 2, cs = (tid & 3) * 16;
        s16x8 t0, t1;
#pragma unroll
        for (int j = 0; j < 8; ++j) {
            t0[j] = (short)Vs[(cs + j) * 65 + dd];
            t1[j] = (short)Vs[(cs + 8 + j) * 65 + dd];
        }
        ushort_t* vout = Vt + ((size_t)(b * 16 + h) * 65536)
                            + (size_t)sblk * 4096 + (cs >> 3) * 512 + dd * 8;
        *reinterpret_cast<s16x8*>(vout) = t0;
        *reinterpret_cast<s16x8*>(vout + 512) = t1;
    }
}

// ---------------- attention v8: QBLK=256, 8 waves, v6 inner structure -------
// Grid 1024 x 512thr. Each K/V tile staged ONCE per 256 q-rows (half the
// staging per FLOP of v6). Per-wave code identical to v6 (32 q-rows/wave).
// Mapping: x=bi&7 (XCD), idx=bi>>3, qt=idx&3, g=( (idx>>2)<<3 )|x.
__global__ __launch_bounds__(512) void attn_mfma8(
    const ushort_t* __restrict__ qb,
    const ushort_t* __restrict__ Kr,
    const ushort_t* __restrict__ Vt,
    const float* __restrict__ cosp, const float* __restrict__ sinp,
    float* __restrict__ out0, float* __restrict__ out1)
{
    __shared__ ushort_t Qs[256 * 64];
    __shared__ ushort_t Ks[64 * 64];
    __shared__ ushort_t Vs[64 * 64];

    const int bi = blockIdx.x;
    const int x = bi & 7;
    const int idx = bi >> 3;
    const int qt = idx & 3;
    const int g = ((idx >> 2) << 3) | x;      // 0..255
    const int h = g & 15, bz = g >> 4;
    const int b = bz >> 1, var = bz & 1;

    const int tid = threadIdx.x;
    const int l = tid & 63, wq = tid >> 6;    // 8 waves
    const int l31 = l & 31, hi = l >> 5;
    const int s0 = qt * 256;

    // ---- stage Q (roped; scale folds 1/8 and log2e) into [d8][row(256)][8] ----
    {
        const int r = tid >> 1;               // 0..255
        const int half = tid & 1;
        const int c32 = half * 32, cco = 32 - c32;
        const float sg = half ? 1.f : -1.f;
        const int p = s0 + r;
        const int pos = var ? ((p & 31) * 32 + (p >> 5)) : p;
        const ushort_t* qrow = qb + (size_t)(b * 1024 + p) * 1024 + h * 64;
        const float* crow = cosp + (size_t)pos * 64 + c32;
        const float* srow = sinp + (size_t)pos * 64 + c32;
        constexpr float SCALE = 0.125f * 1.44269504f;
#pragma unroll
        for (int u = 0; u < 4; ++u) {
            s16x8 xv = ldg8(qrow + c32 + u * 8);
            s16x8 yv = ldg8(qrow + cco + u * 8);
            s16x8 ov;
#pragma unroll
            for (int j = 0; j < 8; ++j) {
                const int e = u * 8 + j;
                ov[j] = (short)f2bf((bf2f((unsigned short)xv[j]) * crow[e]
                         + sg * bf2f((unsigned short)yv[j]) * srow[e]) * SCALE);
            }
            *reinterpret_cast<s16x8*>(&Qs[((half * 4 + u) * 256 + r) * 8]) = ov;
        }
    }
    __syncthreads();

    // Q B-frags: col=q=wq*32+l31, d8 = 2*kc+hi
    s16x8 qf[4];
    {
        const int qrow = wq * 32 + l31;
#pragma unroll
        for (int kc = 0; kc < 4; ++kc)
            qf[kc] = *reinterpret_cast<const s16x8*>(&Qs[((2 * kc + hi) * 256 + qrow) * 8]);
    }

    float l_i = 0.f;
    f32x16 O0, O1;
#pragma unroll
    for (int r = 0; r < 16; ++r) { O0[r] = 0.f; O1[r] = 0.f; }

    const ushort_t* kr_base = Kr + ((size_t)(var * 8 + b) * 16 + h) * 65536;
    const ushort_t* vt_base = Vt + ((size_t)(b * 16 + h)) * 65536;
    const int loff = wq * 512 + l * 8;        // one chunk per wave

    for (int kt = 0; kt < 16; ++kt) {
        __syncthreads();
        gload16(kr_base + (size_t)kt * 4096 + loff, &Ks[wq * 512]);
        gload16(vt_base + (size_t)kt * 4096 + loff, &Vs[wq * 512]);
        __syncthreads();

        // ---- S^T = mfma32(K, Q) ----
        f32x16 St0, St1;
#pragma unroll
        for (int r = 0; r < 16; ++r) { St0[r] = 0.f; St1[r] = 0.f; }
#pragma unroll
        for (int kc = 0; kc < 4; ++kc) {
            const int d8 = 2 * kc + hi;
            s16x8 kf0 = *reinterpret_cast<const s16x8*>(&Ks[d8 * 512 + l31 * 8]);
            s16x8 kf1 = *reinterpret_cast<const s16x8*>(&Ks[d8 * 512 + (32 + l31) * 8]);
            St0 = mfma32(kf0, qf[kc], St0);
            St1 = mfma32(kf1, qf[kc], St1);
        }

        // ---- fixed-max softmax: P = exp2(S) ----
        float rs0 = 0.f, rs1 = 0.f;
#pragma unroll
        for (int r = 0; r < 16; ++r) { St0[r] = __builtin_amdgcn_exp2f(St0[r]); rs0 += St0[r]; }
#pragma unroll
        for (int r = 0; r < 16; ++r) { St1[r] = __builtin_amdgcn_exp2f(St1[r]); rs1 += St1[r]; }
        l_i += rs0 + rs1;

        // ---- P^T frags; O^T += V^T P^T ----
#pragma unroll
        for (int t = 0; t < 2; ++t) {
            unsigned w0, w1, w2, w3, w4, w5, w6, w7;
            if (t == 0) {
                w0 = cvtpk(St0[0], St0[1]);   w1 = cvtpk(St0[2], St0[3]);
                w2 = cvtpk(St0[4], St0[5]);   w3 = cvtpk(St0[6], St0[7]);
                w4 = cvtpk(St0[8], St0[9]);   w5 = cvtpk(St0[10], St0[11]);
                w6 = cvtpk(St0[12], St0[13]); w7 = cvtpk(St0[14], St0[15]);
            } else {
                w0 = cvtpk(St1[0], St1[1]);   w1 = cvtpk(St1[2], St1[3]);
                w2 = cvtpk(St1[4], St1[5]);   w3 = cvtpk(St1[6], St1[7]);
                w4 = cvtpk(St1[8], St1[9]);   w5 = cvtpk(St1[10], St1[11]);
                w6 = cvtpk(St1[12], St1[13]); w7 = cvtpk(St1[14], St1[15]);
            }
            pl32swap(w0, w2, hi);
            pl32swap(w1, w3, hi);
            pl32swap(w4, w6, hi);
            pl32swap(w5, w7, hi);
            const s16x8 pf0 = frag4(w0, w1, w2, w3);
            const s16x8 pf1 = frag4(w4, w5, w6, w7);
#pragma unroll
            for (int cc = 0; cc < 2; ++cc) {
                const int sg8 = 2 * (2 * t + cc) + hi;
                const s16x8 pf = cc ? pf1 : pf0;
                s16x8 vf0 = *reinterpret_cast<const s16x8*>(&Vs[sg8 * 512 + l31 * 8]);
                s16x8 vf1 = *reinterpret_cast<const s16x8*>(&Vs[sg8 * 512 + (32 + l31) * 8]);
                O0 = mfma32(vf0, pf, O0);
                O1 = mfma32(vf1, pf, O1);
            }
        }
    }

    // ---- epilogue ----
    float* outp = var ? out1 : out0;
    const float inv = 1.f / (l_i + __shfl_xor(l_i, 32));
    const int qrow = s0 + wq * 32 + l31;
    float* orow = outp + (size_t)(b * 1024 + qrow) * 1024 + h * 64;
#pragma unroll
    for (int gq = 0; gq < 4; ++gq) {
        const int d0 = 8 * gq + 4 * hi;
        *reinterpret_cast<float4*>(orow + d0) =
            make_float4(O0[4 * gq] * inv, O0[4 * gq + 1] * inv, O0[4 * gq + 2] * inv, O0[4 * gq + 3] * inv);
        *reinterpret_cast<float4*>(orow + 32 + d0) =
            make_float4(O1[4 * gq] * inv, O1[4 * gq + 1] * inv, O1[4 * gq + 2] * inv, O1[4 * gq + 3] * inv);
    }
}

extern "C" void kernel_launch(void* const* d_in, const int* in_sizes, int n_in,
                              void* d_out, int out_size, void* d_ws, size_t ws_size,
                              hipStream_t stream) {
    const float* hidden = (const float*)d_in[0];
    const float* cosp   = (const float*)d_in[1];
    const float* sinp   = (const float*)d_in[2];
    const float* wqkv   = (const float*)d_in[3];
    const float* wo     = (const float*)d_in[4];
    float* out = (float*)d_out;

    char* wsb = (char*)d_ws;
    ushort_t* hb      = (ushort_t*)(wsb);                   // [0,16M)
    ushort_t* wqkvb   = (ushort_t*)(wsb + (16ull << 20));   // [16,22M)
    ushort_t* wob     = (ushort_t*)(wsb + (22ull << 20));   // [22,24M)
    ushort_t* qb      = (ushort_t*)(wsb + (24ull << 20));   // [24,40M)
    ushort_t* kb      = (ushort_t*)(wsb + (40ull << 20));   // [40,56M)
    ushort_t* vb      = (ushort_t*)(wsb + (56ull << 20));   // [56,72M)
    float*    attn0   = (float*)   (wsb + (40ull << 20));   // [40,72M) overlays kb,vb
    ushort_t* Kr      = (ushort_t*)(wsb + (72ull << 20));   // [72,104M)
    ushort_t* Vt      = hb;                                 // overlays hb (dead after QKV GEMM)
    ushort_t* attnavg = (ushort_t*)(wsb + (104ull << 20));  // [104,120M)

    conv3<<<1536, 256, 0, stream>>>(hidden, hb, 8192 * 1024 / 8,
                                    wqkv, wqkvb, 3072 * 1024 / 8,
                                    wo, wob, 1024 * 1024 / 8);

    gemm_mfma<true><<<1536, 256, 0, stream>>>(hb, wqkvb, qb, kb, vb, 8192, 3072, 1024, 24);

    rope_rearrange<<<dim3(16, 16, 8), 256, 0, stream>>>(kb, vb, cosp, sinp, Kr, Vt);

    attn_mfma8<<<1024, 512, 0, stream>>>(qb, Kr, Vt, cosp, sinp, attn0, out);

    avg_to_bf16<<<2048, 256, 0, stream>>>(attn0, out, attnavg, 8192 * 1024 / 8);

    gemm_mfma<false><<<512, 256, 0, stream>>>(attnavg, wob, out, nullptr, nullptr, 8192, 1024, 1024, 8);
}